// Round 7
// baseline (163.689 us; speedup 1.0000x reference)
//
#include <hip/hip_runtime.h>
#include <hip/hip_bf16.h>
#include <math.h>

// Problem constants (match reference)
#define BB 8
#define LL 1024
#define DD 1024
#define KK 128
#define NTS 1000
#define VOCAB 160
#define NATOM 512
#define SCALE 0.08838834764831845f                 // 128^-0.5

typedef __attribute__((ext_vector_type(8))) short short8;   // 8 bf16 = 4 VGPRs
typedef __attribute__((ext_vector_type(4))) float f32x4;    // MFMA accumulator

__device__ __forceinline__ unsigned short f2bf(float x) {
    __hip_bfloat16 h = __float2bfloat16(x);   // RTNE
    return *reinterpret_cast<unsigned short*>(&h);
}
__device__ __forceinline__ float bf2f(unsigned short u) {
    return __uint_as_float(((unsigned int)u) << 16);
}

// ---------------------------------------------------------------------------
// Merged prep kernel (one dispatch, 2725 blocks) -- unchanged from R5/R6:
//   0..2047    : transpose+cast w1 / w2 -> W1t/W2t [n][k] bf16
//   2048..2207 : cast embed_table fp32 -> bf16
//   2208..2719 : cast atom_feat_table fp32 -> bf16
//   2720..2723 : v[d] = sum_c pos_emb_w[c] * pos_feature_w[c,d]
//   2724       : resolve is_molecule dtype
// ---------------------------------------------------------------------------
__global__ __launch_bounds__(256) void prep_kernel(
    const float* __restrict__ w1,
    const float* __restrict__ w2,
    const float* __restrict__ embed_f,
    const float* __restrict__ atom_f,
    const float* __restrict__ pos_emb_w,
    const float* __restrict__ pos_feature_w,
    const void*  __restrict__ is_mol_raw,
    unsigned short* __restrict__ W1t,
    unsigned short* __restrict__ W2t,
    unsigned short* __restrict__ embed_bf,
    unsigned short* __restrict__ atom_bf,
    float* __restrict__ v,
    int*   __restrict__ is_mol_out)
{
    __shared__ float tile[32][33];
    const int blk = blockIdx.x;

    if (blk < 2048) {
        const int which = blk >> 10;                   // 0 -> w1, 1 -> w2
        const int idx = blk & 1023;
        const float* in = which ? w2 : w1;
        unsigned short* out = which ? W2t : W1t;
        const int bx = (idx & 31) * 32, by = (idx >> 5) * 32;
        const int tx = threadIdx.x & 31, ty = threadIdx.x >> 5;  // 32 x 8
        #pragma unroll
        for (int r = 0; r < 32; r += 8)
            tile[ty + r][tx] = in[(size_t)(by + ty + r) * DD + bx + tx];
        __syncthreads();
        #pragma unroll
        for (int r = 0; r < 32; r += 8)
            out[(size_t)(bx + ty + r) * DD + by + tx] = f2bf(tile[tx][ty + r]);
    } else if (blk < 2208) {
        const int e = ((blk - 2048) * 256 + threadIdx.x) * 4;    // < 160*1024
        float4 vv = *(const float4*)&embed_f[e];
        ushort4 o = { f2bf(vv.x), f2bf(vv.y), f2bf(vv.z), f2bf(vv.w) };
        *(ushort4*)&embed_bf[e] = o;
    } else if (blk < 2720) {
        const int e = ((blk - 2208) * 256 + threadIdx.x) * 4;    // < 512*1024
        float4 vv = *(const float4*)&atom_f[e];
        ushort4 o = { f2bf(vv.x), f2bf(vv.y), f2bf(vv.z), f2bf(vv.w) };
        *(ushort4*)&atom_bf[e] = o;
    } else if (blk < 2724) {
        int d = (blk - 2720) * 256 + threadIdx.x;      // < 1024
        float acc = 0.0f;
        #pragma unroll 4
        for (int c = 0; c < KK; ++c)
            acc += pos_emb_w[c] * pos_feature_w[c * DD + d];
        v[d] = acc;
    } else {
        if (threadIdx.x == 0) {
            const int* ip = (const int*)is_mol_raw;
            const unsigned char* cp = (const unsigned char*)is_mol_raw;
            bool all_bin = true;
            for (int i = 0; i < BB; ++i) {
                int x = ip[i];
                if (x != 0 && x != 1) all_bin = false;
            }
            for (int i = 0; i < BB; ++i)
                is_mol_out[i] = all_bin ? (ip[i] != 0) : (cp[i] != 0);
        }
    }
}

// ---------------------------------------------------------------------------
// bf16 MFMA GEMM, BK=256: 32x32 tiles, grid 32x32 = 1024 blocks = 4/CU
// (LDS 33.8 KB/block x 4 = 135 KB/CU; __launch_bounds__(256,4) pins VGPR).
// K-loop is only 4 iterations: each barrier drain amortizes 8 MFMA/wave and
// 8 (MODE0-A) / 4 (bf16) float4 global loads in flight per thread.
// 256 thr = 4 waves, wave-tile 16x16 (one f32x4 acc).
// MODE 0: A = time_table fp32 (cast during staging, rows clamped at NTS-1;
//         junk rows >=1000 never gathered), silu -> bf16 H.
// MODE 1: A = H bf16, bias only -> bf16 E.
// ---------------------------------------------------------------------------
template <int MODE>
__global__ __launch_bounds__(256, 4) void mfma_gemm32(
    const void* __restrict__ Ap,
    const unsigned short* __restrict__ Bt,
    const float* __restrict__ bias,
    unsigned short* __restrict__ Cout)
{
    // +8 ushort pad: row stride 528B = 132 dwords == 4 (mod 32) -> the same
    // conflict-free b128 pattern R5/R6 measured at SQ_LDS_BANK_CONFLICT = 0.
    __shared__ __align__(16) unsigned short As[32][264];
    __shared__ __align__(16) unsigned short Bs[32][264];

    const int tid  = threadIdx.x;
    const int lane = tid & 63;
    const int wave = tid >> 6;
    const int wm = wave >> 1, wn = wave & 1;
    const int quad = lane >> 4, l16 = lane & 15;
    const int mBase = blockIdx.y * 32, nBase = blockIdx.x * 32;

    f32x4 acc = {0.f, 0.f, 0.f, 0.f};

    // Staging map: 32 rows x 256 k; 8 threads per row.
    // A (MODE0, fp32): thread covers 32 floats = 8 float4.
    // A (MODE1, bf16) and B (bf16): 32 shorts = 4 float4.
    const int r = tid >> 3;
    const int koA = (tid & 7) * 32;        // element offset within row
    const int rowB = nBase + r;
    int rowA = mBase + r;
    if (MODE == 0 && rowA >= NTS) rowA = NTS - 1;   // clamp pad rows

    for (int k0 = 0; k0 < DD; k0 += 256) {
        if (MODE == 0) {
            const float* A = (const float*)Ap;
            #pragma unroll
            for (int c = 0; c < 4; ++c) {
                float4 a0 = *(const float4*)&A[(size_t)rowA * DD + k0 + koA + c * 8];
                float4 a1 = *(const float4*)&A[(size_t)rowA * DD + k0 + koA + c * 8 + 4];
                short8 s8;
                s8[0]=f2bf(a0.x); s8[1]=f2bf(a0.y); s8[2]=f2bf(a0.z); s8[3]=f2bf(a0.w);
                s8[4]=f2bf(a1.x); s8[5]=f2bf(a1.y); s8[6]=f2bf(a1.z); s8[7]=f2bf(a1.w);
                *(short8*)&As[r][koA + c * 8] = s8;
            }
        } else {
            const unsigned short* A = (const unsigned short*)Ap;
            #pragma unroll
            for (int c = 0; c < 4; ++c) {
                float4 a = *(const float4*)&A[(size_t)rowA * DD + k0 + koA + c * 8];
                *(float4*)&As[r][koA + c * 8] = a;
            }
        }
        #pragma unroll
        for (int c = 0; c < 4; ++c) {
            float4 b = *(const float4*)&Bt[(size_t)rowB * DD + k0 + koA + c * 8];
            *(float4*)&Bs[r][koA + c * 8] = b;
        }
        __syncthreads();

        #pragma unroll
        for (int kk = 0; kk < 256; kk += 32) {
            short8 af = *(const short8*)&As[wm * 16 + l16][kk + quad * 8];
            short8 bf = *(const short8*)&Bs[wn * 16 + l16][kk + quad * 8];
            acc = __builtin_amdgcn_mfma_f32_16x16x32_bf16(af, bf, acc, 0, 0, 0);
        }
        __syncthreads();
    }

    // C/D layout: col = lane&15, row = quad*4 + reg  [m89-verified]
    const int col = nBase + wn * 16 + l16;
    const float bv = bias[col];
    #pragma unroll
    for (int r4 = 0; r4 < 4; ++r4) {
        const int row = mBase + wm * 16 + quad * 4 + r4;
        float val = acc[r4] + bv;
        if (MODE == 0) val = val / (1.0f + __expf(-val));   // silu
        Cout[(size_t)row * DD + col] = f2bf(val);
    }
}

// ---------------------------------------------------------------------------
// Fused attention + assembly -- unchanged from R5/R6 (passing).
// ---------------------------------------------------------------------------
__global__ __launch_bounds__(256) void fused_all(
    const int*   __restrict__ token_id,
    const int*   __restrict__ node_attr,
    const float* __restrict__ pos,
    const int*   __restrict__ time_step,
    const unsigned short* __restrict__ embed_bf,
    const unsigned short* __restrict__ atom_bf,
    const unsigned short* __restrict__ Ebf,   // [1024, D] bf16 (rows >=1000 junk)
    const float* __restrict__ v,              // [D] fp32
    const int*   __restrict__ is_mol,         // [B] resolved 0/1
    float* __restrict__ out)
{
    __shared__ float4 keys[LL];               // 16 KB
    __shared__ float  sS[8];

    const int blk   = blockIdx.x;             // 0..1023
    const int batch = blk >> 7;
    const int q0    = (blk & 127) << 3;       // 8 queries per block
    const int tid   = threadIdx.x;
    const int lane  = tid & 63, wave = tid >> 6;

    // ---- stage keys --------------------------------------------------------
    #pragma unroll
    for (int i = 0; i < 4; ++i) {
        const int k = tid + i * 256;
        const int t = batch * LL + k;
        const float x = pos[t * 3 + 0];
        const float y = pos[t * 3 + 1];
        const float z = pos[t * 3 + 2];
        const int tok = token_id[t];
        const float n = sqrtf(x * x + y * y + z * z);
        keys[k] = make_float4(x, y, z, tok == 0 ? -1.0f : n);
    }
    __syncthreads();

    // ---- Phase A: s per query (wave handles 2 queries) ---------------------
    #pragma unroll
    for (int qi = 0; qi < 2; ++qi) {
        const int ql = wave * 2 + qi;
        const float4 qk = keys[q0 + ql];      // broadcast read
        float lsum = 0.0f, lws = 0.0f;
        #pragma unroll 4
        for (int i = 0; i < 16; ++i) {
            const float4 kd = keys[lane + i * 64];
            const float dx = qk.x - kd.x, dy = qk.y - kd.y, dz = qk.z - kd.z;
            const float dn = sqrtf(dx * dx + dy * dy + dz * dz);
            const float e = __expf(SCALE / (dn + 1.0f));
            const bool valid = kd.w >= 0.0f;
            const float ev = valid ? e : 0.0f;
            lsum += ev;
            lws  += ev * (valid ? kd.w : 0.0f);
        }
        #pragma unroll
        for (int off = 32; off > 0; off >>= 1) {
            lsum += __shfl_xor(lsum, off);
            lws  += __shfl_xor(lws,  off);
        }
        if (lane == 0)
            sS[ql] = (qk.w < 0.0f) ? 0.0f : (lws / lsum);
    }
    __syncthreads();

    // ---- Phase B: 8 output rows; 2 queries in parallel across halves -------
    const int im   = is_mol[batch];
    const int half = tid >> 7;                 // 0/1
    const int tl   = tid & 127;
    const int j    = tl * 8;                   // 128 thr x 8 dims = 1024
    const float4 v0 = *(const float4*)&v[j];
    const float4 v1 = *(const float4*)&v[j + 4];

    #pragma unroll
    for (int qp = 0; qp < 4; ++qp) {
        const int ql  = qp * 2 + half;
        const int t   = batch * LL + q0 + ql;
        const int tok = token_id[t];
        const int ts  = time_step[t];
        const float s = sS[ql];

        float o[8];
        short8 eb = *(const short8*)&embed_bf[(size_t)tok * DD + j];
        #pragma unroll
        for (int d = 0; d < 8; ++d) o[d] = bf2f((unsigned short)eb[d]);

        if (im) {
            #pragma unroll
            for (int f = 1; f < 9; ++f) {
                const int a = node_attr[t * 9 + f];
                short8 ab = *(const short8*)&atom_bf[(size_t)a * DD + j];
                #pragma unroll
                for (int d = 0; d < 8; ++d) o[d] += bf2f((unsigned short)ab[d]);
            }
        }
        short8 er = *(const short8*)&Ebf[(size_t)ts * DD + j];
        #pragma unroll
        for (int d = 0; d < 8; ++d) o[d] += bf2f((unsigned short)er[d]);

        o[0] += s * v0.x; o[1] += s * v0.y; o[2] += s * v0.z; o[3] += s * v0.w;
        o[4] += s * v1.x; o[5] += s * v1.y; o[6] += s * v1.z; o[7] += s * v1.w;

        float4 w0 = {o[0], o[1], o[2], o[3]};
        float4 w1 = {o[4], o[5], o[6], o[7]};
        *(float4*)&out[(size_t)t * DD + j]     = w0;
        *(float4*)&out[(size_t)t * DD + j + 4] = w1;
    }

    if (tid < 8) {
        const int t = batch * LL + q0 + tid;
        out[(size_t)BB * LL * DD + t] = (keys[q0 + tid].w < 0.0f) ? 1.0f : 0.0f;
    }
}

// ---------------------------------------------------------------------------
extern "C" void kernel_launch(void* const* d_in, const int* in_sizes, int n_in,
                              void* d_out, int out_size, void* d_ws, size_t ws_size,
                              hipStream_t stream)
{
    const int*   token_id      = (const int*)  d_in[0];
    const int*   node_attr     = (const int*)  d_in[1];
    const void*  is_mol_raw    = (const void*) d_in[2];
    const float* pos           = (const float*)d_in[3];
    const int*   time_step     = (const int*)  d_in[4];
    const float* embed_table   = (const float*)d_in[5];
    const float* atom_feat     = (const float*)d_in[6];
    const float* time_table    = (const float*)d_in[7];
    const float* w1            = (const float*)d_in[8];
    const float* b1            = (const float*)d_in[9];
    const float* w2            = (const float*)d_in[10];
    const float* b2            = (const float*)d_in[11];
    const float* pos_emb_w     = (const float*)d_in[12];
    const float* pos_feature_w = (const float*)d_in[13];

    float* out = (float*)d_out;
    char*  ws  = (char*)d_ws;

    // Workspace overlay (~7.5 MB) -- unchanged from R5/R6:
    //   [0,2MB):      W1t bf16 (dead after GEMM1) -> Ebf bf16 (GEMM2 out)
    //   [2MB,4MB):    H bf16
    //   [4MB,6MB):    W2t bf16
    //   [6MB,+320KB): embed_bf
    //   [6.5MB,+1MB): atom_bf
    //   [7.5MB,..):   V fp32[1024], is_mol int[8]
    unsigned short* W1t      = (unsigned short*)(ws);
    unsigned short* Ebf      = (unsigned short*)(ws);
    unsigned short* H        = (unsigned short*)(ws + (2u << 20));
    unsigned short* W2t      = (unsigned short*)(ws + (4u << 20));
    unsigned short* embed_bf = (unsigned short*)(ws + (6u << 20));
    unsigned short* atom_bf  = (unsigned short*)(ws + (6u << 20) + (512u << 10));
    float*          V        = (float*)(ws + (7u << 20) + (512u << 10));
    int*            is_mol_r = (int*)(V + 1024);

    prep_kernel<<<2725, 256, 0, stream>>>(w1, w2, embed_table, atom_feat,
                                          pos_emb_w, pos_feature_w, is_mol_raw,
                                          W1t, W2t, embed_bf, atom_bf,
                                          V, is_mol_r);

    dim3 g(32, 32);
    mfma_gemm32<0><<<g, 256, 0, stream>>>((const void*)time_table, W1t, b1, H);
    mfma_gemm32<1><<<g, 256, 0, stream>>>((const void*)H,          W2t, b2, Ebf);

    fused_all<<<1024, 256, 0, stream>>>(token_id, node_attr, pos, time_step,
                                        embed_bf, atom_bf, Ebf, V,
                                        is_mol_r, out);
}